// Round 10
// baseline (520.123 us; speedup 1.0000x reference)
//
#include <hip/hip_runtime.h>
#include <hip/hip_fp16.h>

#define N_NODES 100000
#define N_EDGES 1600000
#define D 64
#define N_LAYERS 5
#define SCAN_BLOCKS 391   // ceil(N_NODES / 256)

typedef unsigned short u16;
typedef unsigned int u32;
typedef __attribute__((ext_vector_type(8))) short bf16x8;
typedef __attribute__((ext_vector_type(4))) float f32x4;

__device__ __forceinline__ float bf2f(u16 u) {
    union { unsigned int i; float f; } v;
    v.i = ((unsigned int)u) << 16;
    return v.f;
}
__device__ __forceinline__ u16 f2bf(float f) {
    union { float f; unsigned int i; } v;
    v.f = f;
    unsigned int r = v.i + 0x7FFFu + ((v.i >> 16) & 1u);  // round-nearest-even
    return (u16)(r >> 16);
}
__device__ __forceinline__ float bf2f_lo(unsigned int pk) {
    union { unsigned int i; float f; } v;
    v.i = pk << 16;
    return v.f;
}
__device__ __forceinline__ float bf2f_hi(unsigned int pk) {
    union { unsigned int i; float f; } v;
    v.i = pk & 0xFFFF0000u;
    return v.f;
}
// Decode packed edge: src = bits 0..16, w = f16 pattern (sign=0) in bits 17..31
__device__ __forceinline__ float edge_w(u32 d) {
    __half_raw hr;
    hr.x = (u16)(d >> 17);
    return __half2float((__half)hr);
}

// ============================ CSR build (once per launch) ====================

__global__ __launch_bounds__(256) void hist_kernel(
    const int* __restrict__ dst, int* __restrict__ counts)
{
    int e = blockIdx.x * 256 + threadIdx.x;
    if (e < N_EDGES) atomicAdd(&counts[dst[e]], 1);
}

__global__ __launch_bounds__(256) void scan_bsum_kernel(
    const int* __restrict__ counts, int* __restrict__ bsum)
{
    __shared__ int red[256];
    int t = threadIdx.x;
    int i = blockIdx.x * 256 + t;
    red[t] = (i < N_NODES) ? counts[i] : 0;
    __syncthreads();
    for (int off = 128; off > 0; off >>= 1) {
        if (t < off) red[t] += red[t + off];
        __syncthreads();
    }
    if (t == 0) bsum[blockIdx.x] = red[0];
}

__global__ __launch_bounds__(512) void scan_bscan_kernel(
    const int* __restrict__ bsum, int* __restrict__ bscan,
    int* __restrict__ rowptr)
{
    __shared__ int s[512];
    int t = threadIdx.x;
    int v = (t < SCAN_BLOCKS) ? bsum[t] : 0;
    s[t] = v;
    __syncthreads();
    for (int off = 1; off < 512; off <<= 1) {
        int u = (t >= off) ? s[t - off] : 0;
        __syncthreads();
        s[t] += u;
        __syncthreads();
    }
    if (t < SCAN_BLOCKS) bscan[t] = s[t] - v;
    if (t == 511) rowptr[N_NODES] = s[511];
}

__global__ __launch_bounds__(256) void scan_final_kernel(
    const int* __restrict__ counts, const int* __restrict__ bscan,
    int* __restrict__ rowptr, int* __restrict__ cursor)
{
    __shared__ int s[256];
    int t = threadIdx.x;
    int i = blockIdx.x * 256 + t;
    int v = (i < N_NODES) ? counts[i] : 0;
    s[t] = v;
    __syncthreads();
    for (int off = 1; off < 256; off <<= 1) {
        int u = (t >= off) ? s[t - off] : 0;
        __syncthreads();
        s[t] += u;
        __syncthreads();
    }
    if (i < N_NODES) {
        int excl = s[t] - v + bscan[blockIdx.x];
        rowptr[i] = excl;
        cursor[i] = excl;
    }
}

// ============ Placement, XCD-partitioned, ONE dword per edge =================
// Packed record: (f16(w) sans sign)<<17 | src. Halves scattered-store count
// and payload vs int2. Node space split in 8 regions (blockIdx%8) for
// XCD write locality; dst re-read 8x (coalesced).
__global__ __launch_bounds__(256) void place_kernel(
    const int* __restrict__ src, const int* __restrict__ dst,
    const float* __restrict__ ew, int* __restrict__ cursor,
    u32* __restrict__ edges)
{
    const int x  = blockIdx.x & 7;    // region / intended XCD
    const int ci = blockIdx.x >> 3;   // edge chunk
    const int xlo = x * 12500, xhi = xlo + 12500;   // 100000 = 8 * 12500
    const int e0 = ci * 12500;                      // 1.6M = 128 * 12500
    const int e1 = e0 + 12500;
    for (int e = e0 + threadIdx.x; e < e1; e += 256) {
        int d = dst[e];
        if (d >= xlo && d < xhi) {
            int p = atomicAdd(&cursor[d], 1);
            __half hw = __float2half_rn(ew[e]);       // w >= 0: sign bit = 0
            __half_raw hr = (__half_raw)hw;
            edges[p] = ((u32)(hr.x & 0x7FFFu) << 17) | (u32)src[e];
        }
    }
}

// ======================= f32 -> bf16 convert (input x) =======================
__global__ __launch_bounds__(256) void f2bf_kernel(
    const float* __restrict__ in, u16* __restrict__ out)
{
    int i = blockIdx.x * 256 + threadIdx.x;   // one float4 per thread
    if (i >= (N_NODES * D) / 4) return;
    float4 v = ((const float4*)in)[i];
    ushort4 o;
    o.x = f2bf(v.x); o.y = f2bf(v.y); o.z = f2bf(v.z); o.w = f2bf(v.w);
    ((ushort4*)out)[i] = o;
}

// ================== Weight prep: W2T[l][n][k] bf16, k = [Wrel;Wroot] =========
__global__ __launch_bounds__(256) void wprep_kernel(
    const float* __restrict__ Wrel, const float* __restrict__ Wroot,
    u16* __restrict__ W2T)
{
    int i = blockIdx.x * 256 + threadIdx.x;  // over 5*64*128
    if (i >= N_LAYERS * 64 * 128) return;
    int l = i / (64 * 128);
    int rem = i % (64 * 128);
    int n = rem >> 7;   // out dim
    int k = rem & 127;  // input dim (0..63 = rel/agg, 64..127 = root/x)
    float v = (k < 64) ? Wrel[l * 4096 + k * 64 + n]
                       : Wroot[l * 4096 + (k - 64) * 64 + n];
    W2T[i] = f2bf(v);
}

// ========== Aggregation: 2 nodes per wave, bf16x2 dword gather ===============
// Lanes 0-31 serve node (2*wid), lanes 32-63 node (2*wid+1). Each lane loads
// a packed bf16x2 dword (dims 2sl, 2sl+1): ONE gather instruction fetches two
// full 128B rows. Edge records are single dwords: ONE shuffle per edge
// (broadcast packed record, decode src/w per-lane: and/shr/cvt, full-rate).
__global__ __launch_bounds__(256) void agg_kernel(
    const u16* __restrict__ h, const int* __restrict__ rowptr,
    const u32* __restrict__ edges, u16* __restrict__ agg)
{
    int wid  = (blockIdx.x * 256 + threadIdx.x) >> 6;
    int lane = threadIdx.x & 63;
    int sl   = lane & 31;           // sublane: dim pair -> dims 2sl, 2sl+1
    int node = wid * 2 + (lane >> 5);
    if (node >= N_NODES) return;
    int b = rowptr[node];
    int e = rowptr[node + 1];
    float acc0 = 0.f, acc1 = 0.f;
    for (int base = b; base < e; base += 32) {
        int cnt = min(32, e - base);
        u32 rec = 0;
        if (sl < cnt) rec = edges[base + sl];   // per-half coalesced 128B seg
        int j = 0;
        for (; j + 8 <= cnt; j += 8) {
            u32 r0 = (u32)__shfl((int)rec, j + 0, 32);
            u32 r1 = (u32)__shfl((int)rec, j + 1, 32);
            u32 r2 = (u32)__shfl((int)rec, j + 2, 32);
            u32 r3 = (u32)__shfl((int)rec, j + 3, 32);
            u32 r4 = (u32)__shfl((int)rec, j + 4, 32);
            u32 r5 = (u32)__shfl((int)rec, j + 5, 32);
            u32 r6 = (u32)__shfl((int)rec, j + 6, 32);
            u32 r7 = (u32)__shfl((int)rec, j + 7, 32);
            size_t s0 = (size_t)(r0 & 0x1FFFFu), s1 = (size_t)(r1 & 0x1FFFFu);
            size_t s2 = (size_t)(r2 & 0x1FFFFu), s3 = (size_t)(r3 & 0x1FFFFu);
            size_t s4 = (size_t)(r4 & 0x1FFFFu), s5 = (size_t)(r5 & 0x1FFFFu);
            size_t s6 = (size_t)(r6 & 0x1FFFFu), s7 = (size_t)(r7 & 0x1FFFFu);
            unsigned int p0 = *(const unsigned int*)(h + (s0 << 6) + sl * 2);
            unsigned int p1 = *(const unsigned int*)(h + (s1 << 6) + sl * 2);
            unsigned int p2 = *(const unsigned int*)(h + (s2 << 6) + sl * 2);
            unsigned int p3 = *(const unsigned int*)(h + (s3 << 6) + sl * 2);
            unsigned int p4 = *(const unsigned int*)(h + (s4 << 6) + sl * 2);
            unsigned int p5 = *(const unsigned int*)(h + (s5 << 6) + sl * 2);
            unsigned int p6 = *(const unsigned int*)(h + (s6 << 6) + sl * 2);
            unsigned int p7 = *(const unsigned int*)(h + (s7 << 6) + sl * 2);
            float w0 = edge_w(r0), w1 = edge_w(r1);
            float w2 = edge_w(r2), w3 = edge_w(r3);
            float w4 = edge_w(r4), w5 = edge_w(r5);
            float w6 = edge_w(r6), w7 = edge_w(r7);
            acc0 += bf2f_lo(p0) * w0 + bf2f_lo(p1) * w1
                  + bf2f_lo(p2) * w2 + bf2f_lo(p3) * w3
                  + bf2f_lo(p4) * w4 + bf2f_lo(p5) * w5
                  + bf2f_lo(p6) * w6 + bf2f_lo(p7) * w7;
            acc1 += bf2f_hi(p0) * w0 + bf2f_hi(p1) * w1
                  + bf2f_hi(p2) * w2 + bf2f_hi(p3) * w3
                  + bf2f_hi(p4) * w4 + bf2f_hi(p5) * w5
                  + bf2f_hi(p6) * w6 + bf2f_hi(p7) * w7;
        }
        for (; j < cnt; ++j) {
            u32 r = (u32)__shfl((int)rec, j, 32);
            size_t s = (size_t)(r & 0x1FFFFu);
            float w = edge_w(r);
            unsigned int pk = *(const unsigned int*)(h + (s << 6) + sl * 2);
            acc0 += bf2f_lo(pk) * w;
            acc1 += bf2f_hi(pk) * w;
        }
    }
    unsigned int o = ((unsigned int)f2bf(acc1) << 16) | f2bf(acc0);
    *(unsigned int*)(agg + ((size_t)node << 6) + sl * 2) = o;
}

// =================== Dense update via MFMA (no LDS, no barrier) ==============
// Wave = 16 nodes x 64 out-dims = 4 n-tiles x 4 k-steps of 16x16x32 bf16.
// A-frag: lane holds AX[m=lane&15][k=quad*8+j] (doc-verified). B-frag:
// lane holds W2[k=quad*8+j][n=lane&15], read from transposed W2T[n][k].
// D: col(n)=lane&15, row(m)=quad*4+reg (doc-verified). In-place safe:
// wave reads/writes only its own 16 rows; stores data-depend on all loads.
__global__ __launch_bounds__(256) void update_mfma_kernel(
    const u16* __restrict__ hin, const u16* __restrict__ agg,
    const u16* __restrict__ W2T, const float* __restrict__ brel,
    u16* __restrict__ hout_bf, float* __restrict__ hout_f32, int relu)
{
    const int wave = threadIdx.x >> 6;
    const int lane = threadIdx.x & 63;
    const int nb16 = blockIdx.x * 64 + wave * 16;
    const int m = lane & 15;   // node-in-tile for A; out-dim-in-tile for B/D
    const int q = lane >> 4;   // quad

    int anode = nb16 + m;
    size_t rowa = (size_t)((anode < N_NODES) ? anode : 0) << 6;

    bf16x8 a[4];
    a[0] = *(const bf16x8*)(agg + rowa + q * 8);        // k  0..31
    a[1] = *(const bf16x8*)(agg + rowa + 32 + q * 8);   // k 32..63
    a[2] = *(const bf16x8*)(hin + rowa + q * 8);        // k 64..95
    a[3] = *(const bf16x8*)(hin + rowa + 32 + q * 8);   // k 96..127

    bf16x8 bfr[4][4];  // [ntile][kstep]
    #pragma unroll
    for (int nt = 0; nt < 4; ++nt)
        #pragma unroll
        for (int kk = 0; kk < 4; ++kk)
            bfr[nt][kk] = *(const bf16x8*)(W2T + (size_t)(nt * 16 + m) * 128
                                           + kk * 32 + q * 8);

    f32x4 acc[4];
    #pragma unroll
    for (int nt = 0; nt < 4; ++nt) {
        float bv = brel[nt * 16 + m];
        acc[nt] = (f32x4){bv, bv, bv, bv};
    }

    #pragma unroll
    for (int kk = 0; kk < 4; ++kk)
        #pragma unroll
        for (int nt = 0; nt < 4; ++nt)
            acc[nt] = __builtin_amdgcn_mfma_f32_16x16x32_bf16(
                a[kk], bfr[nt][kk], acc[nt], 0, 0, 0);

    #pragma unroll
    for (int nt = 0; nt < 4; ++nt)
        #pragma unroll
        for (int r = 0; r < 4; ++r) {
            int n2 = nb16 + q * 4 + r;           // node (row of D)
            if (n2 < N_NODES) {
                float v = acc[nt][r];
                if (relu) v = fmaxf(v, 0.f);
                int dim = nt * 16 + m;           // out dim (col of D)
                if (hout_f32) hout_f32[(size_t)n2 * 64 + dim] = v;
                else          hout_bf [(size_t)n2 * 64 + dim] = f2bf(v);
            }
        }
}

extern "C" void kernel_launch(void* const* d_in, const int* in_sizes, int n_in,
                              void* d_out, int out_size, void* d_ws, size_t ws_size,
                              hipStream_t stream)
{
    const float* x     = (const float*)d_in[0];
    const int*   ei    = (const int*)d_in[1];   // [2, E] int32
    const float* ew    = (const float*)d_in[2];
    const float* Wrel  = (const float*)d_in[3]; // [5, 64, 64]
    const float* brel  = (const float*)d_in[4]; // [5, 64]
    const float* Wroot = (const float*)d_in[5]; // [5, 64, 64]
    float* out = (float*)d_out;

    const int* src = ei;
    const int* dst = ei + N_EDGES;

    const size_t featb_bytes = (size_t)N_NODES * D * 2;  // 12.8 MB bf16
    char* ws = (char*)d_ws;
    size_t off = 0;
    u16*  hb     = (u16*)(ws + off);  off += featb_bytes;
    u16*  aggb   = (u16*)(ws + off);  off += featb_bytes;
    u16*  W2T    = (u16*)(ws + off);  off += (size_t)N_LAYERS * 64 * 128 * 2;
    int*  counts = (int*)(ws + off);  off += 400000;
    int*  cursor = (int*)(ws + off);  off += 400000;
    int*  rowptr = (int*)(ws + off);  off += 400016;
    int*  bsum   = (int*)(ws + off);  off += 2048;
    int*  bscan  = (int*)(ws + off);  off += 2048;
    u32*  edges  = (u32*)(ws + off);  off += (size_t)N_EDGES * 4;

    const int eblocks = (N_EDGES + 255) / 256;       // 6250
    const int pblocks = 8 * 128;                     // 8 regions x 128 chunks
    const int cblocks = (N_NODES * D / 4 + 255) / 256;
    const int wblocks = (N_LAYERS * 64 * 128 + 255) / 256;  // 160
    const int ablocks = ((N_NODES + 1) / 2 + 3) / 4; // 12500 (2 nodes/wave)
    const int ublocks = (N_NODES + 63) / 64;         // 1563

    // ---- CSR build + converts ----
    hipMemsetAsync(counts, 0, N_NODES * sizeof(int), stream);
    hist_kernel<<<eblocks, 256, 0, stream>>>(dst, counts);
    scan_bsum_kernel<<<SCAN_BLOCKS, 256, 0, stream>>>(counts, bsum);
    scan_bscan_kernel<<<1, 512, 0, stream>>>(bsum, bscan, rowptr);
    scan_final_kernel<<<SCAN_BLOCKS, 256, 0, stream>>>(counts, bscan,
                                                       rowptr, cursor);
    place_kernel<<<pblocks, 256, 0, stream>>>(src, dst, ew, cursor, edges);
    f2bf_kernel<<<cblocks, 256, 0, stream>>>(x, hb);
    wprep_kernel<<<wblocks, 256, 0, stream>>>(Wrel, Wroot, W2T);

    // ---- 5 GraphConv layers (hb updated in place; wave-local rows) ----
    for (int layer = 0; layer < N_LAYERS; ++layer) {
        agg_kernel<<<ablocks, 256, 0, stream>>>(hb, rowptr, edges, aggb);
        int last = (layer == N_LAYERS - 1);
        update_mfma_kernel<<<ublocks, 256, 0, stream>>>(
            hb, aggb, W2T + (size_t)layer * 64 * 128,
            brel + (size_t)layer * D,
            last ? nullptr : hb, last ? out : nullptr,
            last ? 0 : 1);
    }
}